// Round 3
// baseline (106.105 us; speedup 1.0000x reference)
//
#include <hip/hip_runtime.h>
#include <math.h>

// DTLN part-2, ZERO-sync single kernel: every block redundantly computes
// enc -> LN -> LSTM1 -> LSTM2 -> mask/est, then decoder rows are split by block.
// ~640K MACs/block, ~2.4MB weights/block (L2-resident across graph replays).

#define FRAME 1024
#define ENC 256
#define HID 128
#define NBLK 16

__device__ __forceinline__ float sigmoidf_(float x) { return 1.0f / (1.0f + expf(-x)); }

__global__ __launch_bounds__(256) void k_all(
    const float* __restrict__ y1, const float* __restrict__ h1_in,
    const float* __restrict__ c1_in, const float* __restrict__ h2_in,
    const float* __restrict__ c2_in, const float* __restrict__ enc_W,
    const float* __restrict__ gamma, const float* __restrict__ beta,
    const float* __restrict__ Wih1, const float* __restrict__ Whh1,
    const float* __restrict__ bih1, const float* __restrict__ bhh1,
    const float* __restrict__ Wih2, const float* __restrict__ Whh2,
    const float* __restrict__ bih2, const float* __restrict__ bhh2,
    const float* __restrict__ dense_W, const float* __restrict__ dense_b,
    const float* __restrict__ dec_W, float* __restrict__ out)
{
    const int t = threadIdx.x, lane = t & 63, wid = t >> 6, bid = blockIdx.x;
    const int sub = lane >> 2;   // row within 16-row chunk
    const int q   = lane & 3;    // quarter of the K dimension

    __shared__ __align__(16) float encL[ENC];   // raw enc
    __shared__ __align__(16) float encN[ENC];   // normalized
    __shared__ __align__(16) float hA[HID];     // h1_in -> h1
    __shared__ __align__(16) float hB[HID];     // h2_in -> h2
    __shared__ __align__(16) float zb[4 * HID]; // z1 then z2
    __shared__ __align__(16) float es[ENC];     // estimated
    __shared__ float red[8];

    // ---- P1: enc = enc_W @ y1 (256 rows, K=1024). 16 rows/chunk, 4 chunks/wave ----
    {
        const float4* Y4 = reinterpret_cast<const float4*>(y1);
#pragma unroll
        for (int c = 0; c < 4; ++c) {
            const int r = (wid * 4 + c) * 16 + sub;
            const float4* Wr = reinterpret_cast<const float4*>(enc_W) + r * 256 + q * 64;
            const float4* Yq = Y4 + q * 64;
            float4 acc = {0.f, 0.f, 0.f, 0.f};
#pragma unroll 8
            for (int j = 0; j < 64; ++j) {
                const float4 a = Wr[j], b = Yq[j];
                acc.x += a.x * b.x; acc.y += a.y * b.y;
                acc.z += a.z * b.z; acc.w += a.w * b.w;
            }
            float s = acc.x + acc.y + acc.z + acc.w;
            s += __shfl_xor(s, 1); s += __shfl_xor(s, 2);
            if (q == 0) encL[r] = s;
        }
    }
    __syncthreads();

    // ---- P2: global LN (redundant) ----
    {
        const float e = encL[t];
        float s1 = e, s2 = e * e;
#pragma unroll
        for (int o = 32; o > 0; o >>= 1) { s1 += __shfl_down(s1, o); s2 += __shfl_down(s2, o); }
        if (lane == 0) { red[wid] = s1; red[4 + wid] = s2; }
        if (t < HID) hA[t] = h1_in[t];
        __syncthreads();
        const float mean = (red[0] + red[1] + red[2] + red[3]) * (1.f / ENC);
        const float var  = (red[4] + red[5] + red[6] + red[7]) * (1.f / ENC) - mean * mean;
        const float inv  = rsqrtf(var + 1e-7f);
        encN[t] = (e - mean) * inv * gamma[t] + beta[t];
    }
    __syncthreads();

    // ---- P3: z1 = Wih1@encN + Whh1@hA + biases (512 rows, K=256+128). 8 chunks/wave ----
    {
        const float4* xa = reinterpret_cast<const float4*>(encN) + q * 16;
        const float4* xb = reinterpret_cast<const float4*>(hA) + q * 8;
#pragma unroll
        for (int c = 0; c < 8; ++c) {
            const int r = (wid * 8 + c) * 16 + sub;
            const float4* Wa = reinterpret_cast<const float4*>(Wih1) + r * 64 + q * 16;
            const float4* Wb = reinterpret_cast<const float4*>(Whh1) + r * 32 + q * 8;
            float4 acc = {0.f, 0.f, 0.f, 0.f};
#pragma unroll 8
            for (int j = 0; j < 16; ++j) {
                const float4 a = Wa[j], b = xa[j];
                acc.x += a.x * b.x; acc.y += a.y * b.y;
                acc.z += a.z * b.z; acc.w += a.w * b.w;
            }
#pragma unroll 8
            for (int j = 0; j < 8; ++j) {
                const float4 a = Wb[j], b = xb[j];
                acc.x += a.x * b.x; acc.y += a.y * b.y;
                acc.z += a.z * b.z; acc.w += a.w * b.w;
            }
            float s = acc.x + acc.y + acc.z + acc.w;
            s += __shfl_xor(s, 1); s += __shfl_xor(s, 2);
            if (q == 0) zb[r] = s + bih1[r] + bhh1[r];
        }
    }
    __syncthreads();

    // ---- P4: LSTM1 gates (redundant); hA := h1 ----
    if (t < HID) {
        const float i = sigmoidf_(zb[t]);
        const float f = sigmoidf_(zb[HID + t]);
        const float g = tanhf(zb[2 * HID + t]);
        const float o = sigmoidf_(zb[3 * HID + t]);
        const float c = f * c1_in[t] + i * g;
        const float h = o * tanhf(c);
        hA[t] = h;
        hB[t] = h2_in[t];
        if (bid == 0) { out[FRAME + t] = h; out[FRAME + HID + t] = c; }
    }
    __syncthreads();

    // ---- P5: z2 = Wih2@hA + Whh2@hB + biases (512 rows, K=128+128) ----
    {
        const float4* xa = reinterpret_cast<const float4*>(hA) + q * 8;
        const float4* xb = reinterpret_cast<const float4*>(hB) + q * 8;
#pragma unroll
        for (int c = 0; c < 8; ++c) {
            const int r = (wid * 8 + c) * 16 + sub;
            const float4* Wa = reinterpret_cast<const float4*>(Wih2) + r * 32 + q * 8;
            const float4* Wb = reinterpret_cast<const float4*>(Whh2) + r * 32 + q * 8;
            float4 acc = {0.f, 0.f, 0.f, 0.f};
#pragma unroll 8
            for (int j = 0; j < 8; ++j) {
                const float4 a = Wa[j], b = xa[j];
                const float4 a2 = Wb[j], b2 = xb[j];
                acc.x += a.x * b.x + a2.x * b2.x;
                acc.y += a.y * b.y + a2.y * b2.y;
                acc.z += a.z * b.z + a2.z * b2.z;
                acc.w += a.w * b.w + a2.w * b2.w;
            }
            float s = acc.x + acc.y + acc.z + acc.w;
            s += __shfl_xor(s, 1); s += __shfl_xor(s, 2);
            if (q == 0) zb[r] = s + bih2[r] + bhh2[r];
        }
    }
    __syncthreads();

    // ---- P6: LSTM2 gates (redundant); hB := h2 ----
    if (t < HID) {
        const float i = sigmoidf_(zb[t]);
        const float f = sigmoidf_(zb[HID + t]);
        const float g = tanhf(zb[2 * HID + t]);
        const float o = sigmoidf_(zb[3 * HID + t]);
        const float c = f * c2_in[t] + i * g;
        const float h = o * tanhf(c);
        hB[t] = h;
        if (bid == 0) { out[FRAME + 2 * HID + t] = h; out[FRAME + 3 * HID + t] = c; }
    }
    __syncthreads();

    // ---- P7: est = sigmoid(dense_W@hB + b) * encL (256 rows, K=128) ----
    {
        const float4* xd = reinterpret_cast<const float4*>(hB) + q * 8;
#pragma unroll
        for (int c = 0; c < 4; ++c) {
            const int r = (wid * 4 + c) * 16 + sub;
            const float4* Wd = reinterpret_cast<const float4*>(dense_W) + r * 32 + q * 8;
            float4 acc = {0.f, 0.f, 0.f, 0.f};
#pragma unroll 8
            for (int j = 0; j < 8; ++j) {
                const float4 a = Wd[j], b = xd[j];
                acc.x += a.x * b.x; acc.y += a.y * b.y;
                acc.z += a.z * b.z; acc.w += a.w * b.w;
            }
            float s = acc.x + acc.y + acc.z + acc.w;
            s += __shfl_xor(s, 1); s += __shfl_xor(s, 2);
            if (q == 0) es[r] = sigmoidf_(s + dense_b[r]) * encL[r];
        }
    }
    __syncthreads();

    // ---- P8: decoder rows split across blocks: 64 rows/block, 16 rows/wave ----
    {
        const int r = bid * 64 + wid * 16 + sub;
        const float4* Wr = reinterpret_cast<const float4*>(dec_W) + r * 64 + q * 16;
        const float4* xe = reinterpret_cast<const float4*>(es) + q * 16;
        float4 acc = {0.f, 0.f, 0.f, 0.f};
#pragma unroll 8
        for (int j = 0; j < 16; ++j) {
            const float4 a = Wr[j], b = xe[j];
            acc.x += a.x * b.x; acc.y += a.y * b.y;
            acc.z += a.z * b.z; acc.w += a.w * b.w;
        }
        float s = acc.x + acc.y + acc.z + acc.w;
        s += __shfl_xor(s, 1); s += __shfl_xor(s, 2);
        if (q == 0) out[r] = s;
    }
}

extern "C" void kernel_launch(void* const* d_in, const int* in_sizes, int n_in,
                              void* d_out, int out_size, void* d_ws, size_t ws_size,
                              hipStream_t stream) {
    const float* y1      = (const float*)d_in[0];
    const float* h1_in   = (const float*)d_in[1];
    const float* c1_in   = (const float*)d_in[2];
    const float* h2_in   = (const float*)d_in[3];
    const float* c2_in   = (const float*)d_in[4];
    const float* enc_W   = (const float*)d_in[5];
    const float* gamma   = (const float*)d_in[6];
    const float* beta    = (const float*)d_in[7];
    const float* Wih1    = (const float*)d_in[8];
    const float* Whh1    = (const float*)d_in[9];
    const float* bih1    = (const float*)d_in[10];
    const float* bhh1    = (const float*)d_in[11];
    const float* Wih2    = (const float*)d_in[12];
    const float* Whh2    = (const float*)d_in[13];
    const float* bih2    = (const float*)d_in[14];
    const float* bhh2    = (const float*)d_in[15];
    const float* dense_W = (const float*)d_in[16];
    const float* dense_b = (const float*)d_in[17];
    const float* dec_W   = (const float*)d_in[18];

    float* out = (float*)d_out;

    k_all<<<NBLK, 256, 0, stream>>>(y1, h1_in, c1_in, h2_in, c2_in, enc_W,
                                    gamma, beta, Wih1, Whh1, bih1, bhh1,
                                    Wih2, Whh2, bih2, bhh2,
                                    dense_W, dense_b, dec_W, out);
}

// Round 4
// 30.620 us; speedup vs baseline: 3.4652x; 3.4652x over previous
//
#include <hip/hip_runtime.h>
#include <math.h>

// DTLN part-2, single kernel + hand-rolled device-scope spin barriers.
// Work split with ZERO redundant weight reads (~3.4MB fetched once by 256 waves).
// Cross-block data (enc/h1/h2/est) moves via agent-scope atomics (coherent point),
// so barriers need no cache flush. Counters zeroed by a 64B memsetAsync per call.

#define FRAME 1024
#define ENC 256
#define HID 128
#define NBLK 64
#define SCOPE __HIP_MEMORY_SCOPE_AGENT

__device__ __forceinline__ float sigmoidf_(float x) { return 1.0f / (1.0f + expf(-x)); }

__device__ __forceinline__ float wred(float v) {
#pragma unroll
    for (int o = 32; o > 0; o >>= 1) v += __shfl_xor(v, o);
    return v;  // all lanes hold the sum
}

__device__ __forceinline__ void gbar(unsigned* cnt) {
    __syncthreads();  // drains vmcnt: all this block's agent stores complete
    if (threadIdx.x == 0) {
        __hip_atomic_fetch_add(cnt, 1u, __ATOMIC_RELEASE, SCOPE);
        while (__hip_atomic_load(cnt, __ATOMIC_RELAXED, SCOPE) < NBLK)
            __builtin_amdgcn_s_sleep(1);
        asm volatile("" ::: "memory");  // compiler ordering; HW is in-order past the poll
    }
    __syncthreads();
}

__global__ __launch_bounds__(256) void k_all(
    const float* __restrict__ y1, const float* __restrict__ h1_in,
    const float* __restrict__ c1_in, const float* __restrict__ h2_in,
    const float* __restrict__ c2_in, const float* __restrict__ enc_W,
    const float* __restrict__ gamma, const float* __restrict__ beta,
    const float* __restrict__ Wih1, const float* __restrict__ Whh1,
    const float* __restrict__ bih1, const float* __restrict__ bhh1,
    const float* __restrict__ Wih2, const float* __restrict__ Whh2,
    const float* __restrict__ bih2, const float* __restrict__ bhh2,
    const float* __restrict__ dense_W, const float* __restrict__ dense_b,
    const float* __restrict__ dec_W, float* __restrict__ out,
    float* __restrict__ ws)
{
    const int t = threadIdx.x, lane = t & 63, w = t >> 6, bid = blockIdx.x;
    unsigned* cnt = (unsigned*)ws;             // 4 counters, memset to 0 each call
    float* enc_g = ws + 16;                    // 256
    float* h1_g  = ws + 16 + ENC;              // 128
    float* h2_g  = ws + 16 + ENC + HID;        // 128
    float* est_g = ws + 16 + ENC + 2 * HID;    // 256

    __shared__ __align__(16) float encL[ENC];
    __shared__ __align__(16) float encN[ENC];
    __shared__ __align__(16) float hA[HID];
    __shared__ __align__(16) float hB[HID];
    __shared__ __align__(16) float es[ENC];
    __shared__ float zloc[8];
    __shared__ float red[8];

    // ---- S1: enc = enc_W @ y1 (256 rows, K=1024). 4 rows/block, 1/wave ----
    {
        const int r = bid * 4 + w;
        const float4* W4 = reinterpret_cast<const float4*>(enc_W + r * FRAME);
        const float4* Y4 = reinterpret_cast<const float4*>(y1);
        float s = 0.f;
#pragma unroll
        for (int j = 0; j < 4; ++j) {
            const float4 a = W4[j * 64 + lane];
            const float4 b = Y4[j * 64 + lane];
            s += a.x * b.x + a.y * b.y + a.z * b.z + a.w * b.w;
        }
        s = wred(s);
        if (lane == 0) __hip_atomic_store(&enc_g[r], s, __ATOMIC_RELAXED, SCOPE);
    }
    gbar(&cnt[0]);

    // ---- S2: LN (redundant, cheap) + z1 rows + gates1 (block-local) ----
    {
        const float e = __hip_atomic_load(&enc_g[t], __ATOMIC_RELAXED, SCOPE);
        encL[t] = e;
        const float s1 = wred(e);
        const float s2 = wred(e * e);
        if (lane == 0) { red[w] = s1; red[4 + w] = s2; }
        if (t < HID) hA[t] = h1_in[t];
        __syncthreads();
        const float mean = (red[0] + red[1] + red[2] + red[3]) * (1.f / ENC);
        const float var  = (red[4] + red[5] + red[6] + red[7]) * (1.f / ENC) - mean * mean;
        const float inv  = rsqrtf(var + 1e-7f);
        encN[t] = (e - mean) * inv * gamma[t] + beta[t];
        __syncthreads();
        // 8 z1-rows per block: idx = q*4+m -> row = (bid*2+q) + 128*m (m = gate i,f,g,o)
#pragma unroll
        for (int k = 0; k < 2; ++k) {
            const int idx = w * 2 + k;
            const int q = idx >> 2, m = idx & 3;
            const int r = (bid * 2 + q) + HID * m;
            const float4 a = reinterpret_cast<const float4*>(Wih1 + r * ENC)[lane];
            const float4 b = reinterpret_cast<const float4*>(encN)[lane];
            const float2 c = reinterpret_cast<const float2*>(Whh1 + r * HID)[lane];
            const float2 d = reinterpret_cast<const float2*>(hA)[lane];
            float s = a.x * b.x + a.y * b.y + a.z * b.z + a.w * b.w + c.x * d.x + c.y * d.y;
            s = wred(s);
            if (lane == 0) zloc[idx] = s + bih1[r] + bhh1[r];
        }
        __syncthreads();
        if (t < 2) {
            const int unit = bid * 2 + t;
            const float i = sigmoidf_(zloc[t * 4 + 0]);
            const float f = sigmoidf_(zloc[t * 4 + 1]);
            const float g = tanhf(zloc[t * 4 + 2]);
            const float o = sigmoidf_(zloc[t * 4 + 3]);
            const float c = f * c1_in[unit] + i * g;
            const float h = o * tanhf(c);
            __hip_atomic_store(&h1_g[unit], h, __ATOMIC_RELAXED, SCOPE);
            out[FRAME + unit] = h;
            out[FRAME + HID + unit] = c;
        }
    }
    gbar(&cnt[1]);

    // ---- S3: z2 rows + gates2 (block-local) ----
    {
        if (t < HID) {
            hA[t] = __hip_atomic_load(&h1_g[t], __ATOMIC_RELAXED, SCOPE);
            hB[t] = h2_in[t];
        }
        __syncthreads();
#pragma unroll
        for (int k = 0; k < 2; ++k) {
            const int idx = w * 2 + k;
            const int q = idx >> 2, m = idx & 3;
            const int r = (bid * 2 + q) + HID * m;
            const float2 a = reinterpret_cast<const float2*>(Wih2 + r * HID)[lane];
            const float2 b = reinterpret_cast<const float2*>(hA)[lane];
            const float2 c = reinterpret_cast<const float2*>(Whh2 + r * HID)[lane];
            const float2 d = reinterpret_cast<const float2*>(hB)[lane];
            float s = a.x * b.x + a.y * b.y + c.x * d.x + c.y * d.y;
            s = wred(s);
            if (lane == 0) zloc[idx] = s + bih2[r] + bhh2[r];
        }
        __syncthreads();
        if (t < 2) {
            const int unit = bid * 2 + t;
            const float i = sigmoidf_(zloc[t * 4 + 0]);
            const float f = sigmoidf_(zloc[t * 4 + 1]);
            const float g = tanhf(zloc[t * 4 + 2]);
            const float o = sigmoidf_(zloc[t * 4 + 3]);
            const float c = f * c2_in[unit] + i * g;
            const float h = o * tanhf(c);
            __hip_atomic_store(&h2_g[unit], h, __ATOMIC_RELAXED, SCOPE);
            out[FRAME + 2 * HID + unit] = h;
            out[FRAME + 3 * HID + unit] = c;
        }
    }
    gbar(&cnt[2]);

    // ---- S4: est = sigmoid(dense_W@h2 + b) * enc (256 rows, K=128). 4/block ----
    {
        if (t < HID) hB[t] = __hip_atomic_load(&h2_g[t], __ATOMIC_RELAXED, SCOPE);
        __syncthreads();
        const int r = bid * 4 + w;
        const float2 a = reinterpret_cast<const float2*>(dense_W + r * HID)[lane];
        const float2 b = reinterpret_cast<const float2*>(hB)[lane];
        float s = a.x * b.x + a.y * b.y;
        s = wred(s);
        if (lane == 0) {
            const float m_ = sigmoidf_(s + dense_b[r]);
            __hip_atomic_store(&est_g[r], m_ * encL[r], __ATOMIC_RELAXED, SCOPE);
        }
    }
    gbar(&cnt[3]);

    // ---- S5: decoded = dec_W @ est (1024 rows, K=256). 16/block, 4/wave ----
    {
        es[t] = __hip_atomic_load(&est_g[t], __ATOMIC_RELAXED, SCOPE);
        __syncthreads();
        const float4* xe = reinterpret_cast<const float4*>(es);
        const float4 b = xe[lane];
#pragma unroll
        for (int j = 0; j < 4; ++j) {
            const int r = bid * 16 + w * 4 + j;
            const float4 a = reinterpret_cast<const float4*>(dec_W + r * ENC)[lane];
            float s = a.x * b.x + a.y * b.y + a.z * b.z + a.w * b.w;
            s = wred(s);
            if (lane == 0) out[r] = s;
        }
    }
}

extern "C" void kernel_launch(void* const* d_in, const int* in_sizes, int n_in,
                              void* d_out, int out_size, void* d_ws, size_t ws_size,
                              hipStream_t stream) {
    const float* y1      = (const float*)d_in[0];
    const float* h1_in   = (const float*)d_in[1];
    const float* c1_in   = (const float*)d_in[2];
    const float* h2_in   = (const float*)d_in[3];
    const float* c2_in   = (const float*)d_in[4];
    const float* enc_W   = (const float*)d_in[5];
    const float* gamma   = (const float*)d_in[6];
    const float* beta    = (const float*)d_in[7];
    const float* Wih1    = (const float*)d_in[8];
    const float* Whh1    = (const float*)d_in[9];
    const float* bih1    = (const float*)d_in[10];
    const float* bhh1    = (const float*)d_in[11];
    const float* Wih2    = (const float*)d_in[12];
    const float* Whh2    = (const float*)d_in[13];
    const float* bih2    = (const float*)d_in[14];
    const float* bhh2    = (const float*)d_in[15];
    const float* dense_W = (const float*)d_in[16];
    const float* dense_b = (const float*)d_in[17];
    const float* dec_W   = (const float*)d_in[18];

    float* out = (float*)d_out;
    float* ws  = (float*)d_ws;

    // Zero the 4 barrier counters (d_ws is poisoned 0xAA before timing).
    hipMemsetAsync(ws, 0, 64, stream);
    k_all<<<NBLK, 256, 0, stream>>>(y1, h1_in, c1_in, h2_in, c2_in, enc_W,
                                    gamma, beta, Wih1, Whh1, bih1, bhh1,
                                    Wih2, Whh2, bih2, bhh2,
                                    dense_W, dense_b, dec_W, out, ws);
}

// Round 5
// 29.515 us; speedup vs baseline: 3.5950x; 1.0374x over previous
//
#include <hip/hip_runtime.h>
#include <math.h>

// DTLN part-2, single kernel, zero redundant weight reads, 4 spin barriers.
// ALL weights prefetched into registers at kernel start (no dependence on
// computed data), so HBM latency is paid once and overlaps every stage.
// Cross-block traffic: enc(256), h1(128), h2(128), est(256) floats via
// agent-scope atomics. Barrier = count(RMW once per block) + flag poll.

#define FRAME 1024
#define ENC 256
#define HID 128
#define NBLK 64
#define SCOPE __HIP_MEMORY_SCOPE_AGENT

__device__ __forceinline__ float sigmoidf_(float x) { return 1.0f / (1.0f + __expf(-x)); }
__device__ __forceinline__ float tanhf_(float x) { return 2.0f * sigmoidf_(2.0f * x) - 1.0f; }

__device__ __forceinline__ float wred(float v) {
#pragma unroll
    for (int o = 32; o > 0; o >>= 1) v += __shfl_xor(v, o);
    return v;
}

// counters live in ws[0..255] (ints): barrier i: cnt at i*64, flag at i*64+32
__device__ __forceinline__ void gbar(unsigned* base, int which) {
    unsigned* cnt  = base + which * 64;
    unsigned* flag = base + which * 64 + 32;
    __syncthreads();
    if (threadIdx.x == 0) {
        const unsigned old = __hip_atomic_fetch_add(cnt, 1u, __ATOMIC_ACQ_REL, SCOPE);
        if (old == NBLK - 1u) {
            __hip_atomic_store(flag, 1u, __ATOMIC_RELEASE, SCOPE);
        } else {
            while (__hip_atomic_load(flag, __ATOMIC_ACQUIRE, SCOPE) == 0u)
                __builtin_amdgcn_s_sleep(4);
        }
    }
    __syncthreads();
}

__global__ __launch_bounds__(256, 1) void k_all(
    const float* __restrict__ y1, const float* __restrict__ h1_in,
    const float* __restrict__ c1_in, const float* __restrict__ h2_in,
    const float* __restrict__ c2_in, const float* __restrict__ enc_W,
    const float* __restrict__ gamma, const float* __restrict__ beta,
    const float* __restrict__ Wih1, const float* __restrict__ Whh1,
    const float* __restrict__ bih1, const float* __restrict__ bhh1,
    const float* __restrict__ Wih2, const float* __restrict__ Whh2,
    const float* __restrict__ bih2, const float* __restrict__ bhh2,
    const float* __restrict__ dense_W, const float* __restrict__ dense_b,
    const float* __restrict__ dec_W, float* __restrict__ out,
    float* __restrict__ ws)
{
    const int t = threadIdx.x, lane = t & 63, w = t >> 6, bid = blockIdx.x;
    unsigned* bars = (unsigned*)ws;
    float* enc_g = ws + 256;
    float* h1_g  = ws + 512;
    float* h2_g  = ws + 640;
    float* est_g = ws + 768;

    __shared__ __align__(16) float encL[ENC];
    __shared__ __align__(16) float encN[ENC];
    __shared__ __align__(16) float hA[HID];
    __shared__ __align__(16) float hB[HID];
    __shared__ __align__(16) float es[ENC];
    __shared__ float zloc[8];
    __shared__ float red[8];

    // ================= PREFETCH EVERYTHING (no data dependences) =============
    // S1: enc row r1 = bid*4+w, K=1024
    const int r1 = bid * 4 + w;
    float4 ew[4], yv[4];
    {
        const float4* W4 = reinterpret_cast<const float4*>(enc_W + r1 * FRAME);
        const float4* Y4 = reinterpret_cast<const float4*>(y1);
#pragma unroll
        for (int j = 0; j < 4; ++j) { ew[j] = W4[j * 64 + lane]; yv[j] = Y4[j * 64 + lane]; }
    }
    // S2/S3: 2 rows each per wave; idx = w*2+k; unit q=idx>>2; gate m=idx&3
    float4 wi1[2]; float2 wh1[2], wi2[2], wh2[2]; float b1s[2], b2s[2];
#pragma unroll
    for (int k = 0; k < 2; ++k) {
        const int idx = w * 2 + k, q = idx >> 2, m = idx & 3;
        const int r = (bid * 2 + q) + HID * m;
        wi1[k] = reinterpret_cast<const float4*>(Wih1 + r * ENC)[lane];
        wh1[k] = reinterpret_cast<const float2*>(Whh1 + r * HID)[lane];
        wi2[k] = reinterpret_cast<const float2*>(Wih2 + r * HID)[lane];
        wh2[k] = reinterpret_cast<const float2*>(Whh2 + r * HID)[lane];
        b1s[k] = bih1[r] + bhh1[r];
        b2s[k] = bih2[r] + bhh2[r];
    }
    // S4: dense row r4 = bid*4+w, K=128
    const int r4 = bid * 4 + w;
    const float2 dw = reinterpret_cast<const float2*>(dense_W + r4 * HID)[lane];
    const float db = dense_b[r4];
    // S5: dec rows r5 = bid*16 + w*4 + j, K=256
    float4 dc[4];
#pragma unroll
    for (int j = 0; j < 4; ++j)
        dc[j] = reinterpret_cast<const float4*>(dec_W + (bid * 16 + w * 4 + j) * ENC)[lane];
    // small vectors
    const float gam = gamma[t], bet = beta[t];
    const float2 h1v = reinterpret_cast<const float2*>(h1_in)[lane];
    const float2 h2v = reinterpret_cast<const float2*>(h2_in)[lane];
    const float c1u = (t < 2) ? c1_in[bid * 2 + t] : 0.f;
    const float c2u = (t < 2) ? c2_in[bid * 2 + t] : 0.f;
    const float h2t = (t < HID) ? h2_in[t] : 0.f;

    // input-only lane-partials of the recurrent halves (off critical path)
    float ph1[2], ph2[2];
#pragma unroll
    for (int k = 0; k < 2; ++k) {
        ph1[k] = wh1[k].x * h1v.x + wh1[k].y * h1v.y;
        ph2[k] = wh2[k].x * h2v.x + wh2[k].y * h2v.y;
    }

    // ================= S1: enc = enc_W @ y1 =================
    {
        float s = 0.f;
#pragma unroll
        for (int j = 0; j < 4; ++j)
            s += ew[j].x * yv[j].x + ew[j].y * yv[j].y + ew[j].z * yv[j].z + ew[j].w * yv[j].w;
        s = wred(s);
        if (lane == 0) __hip_atomic_store(&enc_g[r1], s, __ATOMIC_RELAXED, SCOPE);
    }
    gbar(bars, 0);

    // ================= S2: LN + z1(Wih1 part) + gates1 =================
    {
        const float e = __hip_atomic_load(&enc_g[t], __ATOMIC_RELAXED, SCOPE);
        encL[t] = e;
        const float s1 = wred(e);
        const float s2 = wred(e * e);
        if (lane == 0) { red[w] = s1; red[4 + w] = s2; }
        __syncthreads();
        const float mean = (red[0] + red[1] + red[2] + red[3]) * (1.f / ENC);
        const float var  = (red[4] + red[5] + red[6] + red[7]) * (1.f / ENC) - mean * mean;
        const float inv  = rsqrtf(var + 1e-7f);
        encN[t] = (e - mean) * inv * gam + bet;
        __syncthreads();
        const float4 xb = reinterpret_cast<const float4*>(encN)[lane];
#pragma unroll
        for (int k = 0; k < 2; ++k) {
            float p = wi1[k].x * xb.x + wi1[k].y * xb.y + wi1[k].z * xb.z + wi1[k].w * xb.w + ph1[k];
            p = wred(p);
            if (lane == 0) zloc[w * 2 + k] = p + b1s[k];
        }
        __syncthreads();
        if (t < 2) {
            const int unit = bid * 2 + t;
            const float i = sigmoidf_(zloc[t * 4 + 0]);
            const float f = sigmoidf_(zloc[t * 4 + 1]);
            const float g = tanhf_(zloc[t * 4 + 2]);
            const float o = sigmoidf_(zloc[t * 4 + 3]);
            const float c = f * c1u + i * g;
            const float h = o * tanhf_(c);
            __hip_atomic_store(&h1_g[unit], h, __ATOMIC_RELAXED, SCOPE);
            out[FRAME + unit] = h;
            out[FRAME + HID + unit] = c;
        }
    }
    gbar(bars, 1);

    // ================= S3: z2 + gates2 =================
    {
        if (t < HID) hA[t] = __hip_atomic_load(&h1_g[t], __ATOMIC_RELAXED, SCOPE);
        __syncthreads();
        const float2 xa = reinterpret_cast<const float2*>(hA)[lane];
#pragma unroll
        for (int k = 0; k < 2; ++k) {
            float p = wi2[k].x * xa.x + wi2[k].y * xa.y + ph2[k];
            p = wred(p);
            if (lane == 0) zloc[w * 2 + k] = p + b2s[k];
        }
        __syncthreads();
        if (t < 2) {
            const int unit = bid * 2 + t;
            const float i = sigmoidf_(zloc[t * 4 + 0]);
            const float f = sigmoidf_(zloc[t * 4 + 1]);
            const float g = tanhf_(zloc[t * 4 + 2]);
            const float o = sigmoidf_(zloc[t * 4 + 3]);
            const float c = f * c2u + i * g;
            const float h = o * tanhf_(c);
            __hip_atomic_store(&h2_g[unit], h, __ATOMIC_RELAXED, SCOPE);
            out[FRAME + 2 * HID + unit] = h;
            out[FRAME + 3 * HID + unit] = c;
        }
    }
    gbar(bars, 2);

    // ================= S4: est = sigmoid(dense@h2 + b) * enc =================
    {
        if (t < HID) hB[t] = __hip_atomic_load(&h2_g[t], __ATOMIC_RELAXED, SCOPE);
        __syncthreads();
        const float2 xb = reinterpret_cast<const float2*>(hB)[lane];
        float p = dw.x * xb.x + dw.y * xb.y;
        p = wred(p);
        if (lane == 0) {
            const float m_ = sigmoidf_(p + db);
            __hip_atomic_store(&est_g[r4], m_ * encL[r4], __ATOMIC_RELAXED, SCOPE);
        }
    }
    gbar(bars, 3);

    // ================= S5: decoded = dec_W @ est =================
    {
        es[t] = __hip_atomic_load(&est_g[t], __ATOMIC_RELAXED, SCOPE);
        __syncthreads();
        const float4 xe = reinterpret_cast<const float4*>(es)[lane];
#pragma unroll
        for (int j = 0; j < 4; ++j) {
            float s = dc[j].x * xe.x + dc[j].y * xe.y + dc[j].z * xe.z + dc[j].w * xe.w;
            s = wred(s);
            if (lane == 0) out[bid * 16 + w * 4 + j] = s;
        }
    }
}

extern "C" void kernel_launch(void* const* d_in, const int* in_sizes, int n_in,
                              void* d_out, int out_size, void* d_ws, size_t ws_size,
                              hipStream_t stream) {
    const float* y1      = (const float*)d_in[0];
    const float* h1_in   = (const float*)d_in[1];
    const float* c1_in   = (const float*)d_in[2];
    const float* h2_in   = (const float*)d_in[3];
    const float* c2_in   = (const float*)d_in[4];
    const float* enc_W   = (const float*)d_in[5];
    const float* gamma   = (const float*)d_in[6];
    const float* beta    = (const float*)d_in[7];
    const float* Wih1    = (const float*)d_in[8];
    const float* Whh1    = (const float*)d_in[9];
    const float* bih1    = (const float*)d_in[10];
    const float* bhh1    = (const float*)d_in[11];
    const float* Wih2    = (const float*)d_in[12];
    const float* Whh2    = (const float*)d_in[13];
    const float* bih2    = (const float*)d_in[14];
    const float* bhh2    = (const float*)d_in[15];
    const float* dense_W = (const float*)d_in[16];
    const float* dense_b = (const float*)d_in[17];
    const float* dec_W   = (const float*)d_in[18];

    float* out = (float*)d_out;
    float* ws  = (float*)d_ws;

    // zero the barrier counters/flags (ws is poisoned 0xAA once before timing)
    hipMemsetAsync(ws, 0, 1024, stream);
    k_all<<<NBLK, 256, 0, stream>>>(y1, h1_in, c1_in, h2_in, c2_in, enc_W,
                                    gamma, beta, Wih1, Whh1, bih1, bhh1,
                                    Wih2, Whh2, bih2, bhh2,
                                    dense_W, dense_b, dec_W, out, ws);
}